// Round 11
// baseline (45.208 us; speedup 1.0000x reference)
//
#include <hip/hip_runtime.h>
#include <math.h>

#define B 8
#define H 384
#define W 384
#define HW (H*W)
#define NTOT (B*HW)
#define INF_I 10000
#define NFB 576            // node-1 blocks: 256 thr / 256 pixels each
#define NWK 512            // node-2 workers: (image, 6-row stripe)
#define WPL 8              // workers per counter line (64 lines)

// ws layout (bytes):
//   cnt   @ 0      : 64 lines x 256B (uint counter per line)
//   slot  @ 16384  : 512 lines x 256B (ull slot per worker)
//   part2 @ 147456 : NFB*25 doubles (115200 B)
//   bitsG @ 262656 : 8 images x 2304 u64 (147456 B) target bitmasks
//   sumA  @ 410112 : HW float (sum_b |p - t|)
#define WS_SLOT  16384
#define WS_PART2 147456
#define WS_BITS  262656
#define WS_SUMA  410112

// ---------------- node 1: fused BCE/dice/sumA + target bit-pack ----------------
__global__ __launch_bounds__(256) void k_stage1(const float* __restrict__ pred,
                                                const int* __restrict__ tgt,
                                                float* __restrict__ sumA,
                                                double* __restrict__ part2,
                                                unsigned long long* __restrict__ bitsG,
                                                char* __restrict__ syncws) {
    __shared__ float lds[4][25];
    int tid = threadIdx.x, bid = blockIdx.x;
    int lane = tid & 63;
    if (bid == 0 && tid < 64) *(unsigned*)(syncws + tid * 256) = 0u;  // reset counters

    int pix = bid * 256 + tid;
    float vals[25];                    // 0=bce, 1+b=p, 9+b=p*t, 17+b=t
    float sA = 0.f, bce = 0.f;
#pragma unroll
    for (int b = 0; b < 8; ++b) {
        float x = pred[b * HW + pix];
        int t = tgt[b * HW + pix];
        unsigned long long mb = __ballot(t != 0);          // bit-pack (free: t already loaded)
        if (lane == 0) bitsG[b * 2304 + (pix >> 6)] = mb;
        float e = expf(-fabsf(x));
        float r = 1.f / (1.f + e);
        float p = (x >= 0.f) ? r : 1.f - r;                // stable sigmoid
        bce += fmaxf(x, 0.f) + log1pf(e) - x * (float)t;   // softplus - x*t
        vals[1 + b] = p;
        vals[9 + b] = t ? p : 0.f;
        vals[17 + b] = (float)t;
        sA += t ? 1.f - p : p;
    }
    sumA[pix] = sA;
    vals[0] = bce;
#pragma unroll
    for (int k = 0; k < 25; ++k)
#pragma unroll
        for (int o = 32; o; o >>= 1) vals[k] += __shfl_down(vals[k], o);
    int wave = tid >> 6;
    if (lane == 0)
#pragma unroll
        for (int k = 0; k < 25; ++k) lds[wave][k] = vals[k];
    __syncthreads();
    if (tid < 25) {
        double s = (double)lds[0][tid] + (double)lds[1][tid]
                 + (double)lds[2][tid] + (double)lds[3][tid];
        part2[bid * 25 + tid] = s;
    }
}

// ---------------- node 2: block-local vert EDT + row envelope + tail ----------------
__global__ __launch_bounds__(384) void k_rows(const unsigned long long* __restrict__ bitsG,
                                              const float* __restrict__ sumA,
                                              const double* __restrict__ part2,
                                              char* __restrict__ syncws,
                                              float* __restrict__ out) {
    __shared__ unsigned long long lbits[2304];
    __shared__ float lfp[6][412], lfn[6][412];
    __shared__ double wpart[6];
    __shared__ double sval[25];
    int tid = threadIdx.x, bid = blockIdx.x;

    if (bid == NWK) {
        // ================= combiner =================
        if (tid < 200) {
            int v = tid >> 3, sub = tid & 7;
            double s = 0.0;
            for (int blk = sub; blk < NFB; blk += 8) s += part2[blk * 25 + v];
#pragma unroll
            for (int o = 4; o; o >>= 1) s += __shfl_down(s, o, 8);
            if (sub == 0) sval[v] = s;
        }
        __syncthreads();
        double s2 = 0.0;
        if (tid < 64) {
            unsigned c;
            do {
                c = atomicAdd((unsigned*)(syncws + tid * 256), 0u);
                if (__all(c == WPL)) break;
                __builtin_amdgcn_s_sleep(1);
            } while (1);
            double r[8];
#pragma unroll
            for (int j = 0; j < 8; ++j)
                r[j] = __longlong_as_double(atomicAdd(
                    (unsigned long long*)(syncws + WS_SLOT + (j * 64 + tid) * 256), 0ull));
            s2 = ((((((r[0] + r[1]) + r[2]) + r[3]) + r[4]) + r[5]) + r[6]) + r[7];
#pragma unroll
            for (int o = 32; o; o >>= 1) s2 += __shfl_down(s2, o);
        }
        if (tid == 0) {
            double bce = sval[0] / (double)NTOT;
            double dsum = 0.0;
            for (int bb = 0; bb < 8; ++bb)
                dsum += (2.0 * sval[9 + bb] + 1e-5) / (sval[1 + bb] + sval[17 + bb] + 1e-5);
            double dice = dsum / 8.0;
            double loss1 = 0.5 * bce + (1.0 - dice);
            double loss2 = s2 / ((double)B * (double)B * (double)HW);
            out[0] = (float)(0.7 * loss1 + 0.03 * loss2);
        }
        return;
    }

    // ================= worker: (image b, 6-row stripe) =================
    int b = bid >> 6, stripe = bid & 63;
    for (int i = tid; i < 2304; i += 384) lbits[i] = bitsG[b * 2304 + i];
    __syncthreads();

    int wv = tid >> 6, lane = tid & 63;
    int h = stripe * 6 + wv;                 // one row per wave
    int kup = h, kdn = H - 1 - h;
    int kmax = kup > kdn ? kup : kdn;

    // ---- vertical EDT via broadcast bit probes (exact, full column in LDS) ----
    for (int g = 0; g < 6; ++g) {
        int w = g * 64 + lane;
        int c = (int)((lbits[h * 6 + g] >> lane) & 1ull);
        int dP = c ? 0 : INF_I;
        int dN = c ? INF_I : 0;
        for (int k = 1; k <= kmax; ++k) {
            if (__all(dP < INF_I && dN < INF_I)) break;
            int vu = (k <= kup), vd = (k <= kdn);
            unsigned long long mu = vu ? lbits[(h - k) * 6 + g] : 0ull;
            unsigned long long md = vd ? lbits[(h + k) * 6 + g] : 0ull;
            int bu = (int)((mu >> lane) & 1ull);
            int bd = (int)((md >> lane) & 1ull);
            if (dP == INF_I && ((vu & bu) | (vd & bd))) dP = k;
            if (dN == INF_I && ((vu & (bu ^ 1)) | (vd & (bd ^ 1)))) dN = k;
        }
        int s = w + (w >> 4);
        lfp[wv][s] = (float)dP * (float)dP;  // exact: d<=1e4 -> d^2<=1e8
        lfn[wv][s] = (float)dN * (float)dN;
    }
    // wave-local producer/consumer: this wave only reads its own row
    asm volatile("s_waitcnt lgkmcnt(0)" ::: "memory");

    // ---- row lower-envelope (17-tap window + provable full-row fallback) ----
    int base = 6 * lane - 8;
    float rp[22], rn[22];
#pragma unroll
    for (int r = 0; r < 22; ++r) {
        int j = base + r;
        j = j < 0 ? 0 : (j > W - 1 ? W - 1 : j);
        int s = j + (j >> 4);
        rp[r] = lfp[wv][s];
        rn[r] = lfn[wv][s];
    }
    const float DD[17] = {64.f,49.f,36.f,25.f,16.f,9.f,4.f,1.f,0.f,
                          1.f,4.f,9.f,16.f,25.f,36.f,49.f,64.f};
    float partial = 0.f;
#pragma unroll
    for (int q = 0; q < 6; ++q) {
        int i = 6 * lane + q;
        float Dp = 3.0e38f, Dn = 3.0e38f;
#pragma unroll
        for (int tt = 0; tt < 17; ++tt) {
            Dp = fminf(Dp, rp[q + tt] + DD[tt]);
            Dn = fminf(Dn, rn[q + tt] + DD[tt]);
        }
        if (Dp > 64.f || Dn > 64.f) {        // exactness not proven -> full row
            float fi = (float)i;
            for (int j = 0; j < W; ++j) {
                int s = j + (j >> 4);
                float d = fi - (float)j;
                Dp = fminf(Dp, fmaf(d, d, lfp[wv][s]));
                Dn = fminf(Dn, fmaf(d, d, lfn[wv][s]));
            }
        }
        float sdf = fabsf(sqrtf(Dp) - sqrtf(Dn));
        partial += sdf * sumA[h * W + i];
    }
    double v = partial;
#pragma unroll
    for (int o = 32; o; o >>= 1) v += __shfl_down(v, o);
    if (lane == 0) wpart[wv] = v;
    __syncthreads();

    if (tid == 0) {
        double bp = ((((wpart[0] + wpart[1]) + wpart[2]) + wpart[3]) + wpart[4]) + wpart[5];
        atomicExch((unsigned long long*)(syncws + WS_SLOT + bid * 256),
                   __double_as_longlong(bp));
        asm volatile("s_waitcnt vmcnt(0)" ::: "memory");   // slot visible before cnt
        atomicAdd((unsigned*)(syncws + (bid >> 3) * 256), 1u);
    }
}

extern "C" void kernel_launch(void* const* d_in, const int* in_sizes, int n_in,
                              void* d_out, int out_size, void* d_ws, size_t ws_size,
                              hipStream_t stream) {
    const float* pred = (const float*)d_in[0];
    const int* tgt = (const int*)d_in[1];
    float* out = (float*)d_out;
    char* ws = (char*)d_ws;
    double* part2 = (double*)(ws + WS_PART2);
    unsigned long long* bitsG = (unsigned long long*)(ws + WS_BITS);
    float* sumA = (float*)(ws + WS_SUMA);

    k_stage1<<<NFB, 256, 0, stream>>>(pred, tgt, sumA, part2, bitsG, ws);
    k_rows<<<NWK + 1, 384, 0, stream>>>(bitsG, sumA, part2, ws, out);
}

// Round 12
// 26.968 us; speedup vs baseline: 1.6764x; 1.6764x over previous
//
#include <hip/hip_runtime.h>
#include <math.h>

#define B 8
#define H 384
#define W 384
#define HW (H*W)
#define NTOT (B*HW)
#define INF_I 10000
#define NFB 192            // fused-reduction blocks in stage1
#define NVB 48             // vertical-EDT blocks in stage1
#define NWK 512            // row worker blocks (6 rows = 6 waves each)
#define WPL 8              // workers per counter line (64 lines)

// ws layout (bytes):
//   cnt   @ 0      : 64 lines x 256B   (uint counter per line, 8 writers each)
//   slot  @ 16384  : 512 lines x 256B  (ull slot per worker block)
//   part2 @ 147456 : NFB*25 doubles (38400 B)  fused partials
//   g2u   @ 188416 : NTOT uint   (dpos | dneg<<16)
//   sumA  @ 4907008: HW float    (sum_b |p - t|)
#define WS_SLOT  16384
#define WS_PART2 147456
#define WS_G2U   188416
#define WS_SUMA  4907008

// ---------------- launch 1: fused BCE/dice/sumA + vertical EDT ----------------
__global__ __launch_bounds__(768) void k_stage1(const float* __restrict__ pred,
                                                const int* __restrict__ tgt,
                                                float* __restrict__ sumA,
                                                double* __restrict__ part2,
                                                unsigned* __restrict__ g2u,
                                                char* __restrict__ syncws) {
    __shared__ float lds[12][25];
    __shared__ unsigned bmsh[12][64];
    int tid = threadIdx.x;

    if (blockIdx.x < NFB) {
        // ---- fused BCE + dice partials + sumA: one pixel/thread, 8 batches ----
        int pix = blockIdx.x * 768 + tid;
        float vals[25];                    // 0=bce, 1+b=p, 9+b=p*t, 17+b=t
        float sA = 0.f, bce = 0.f;
#pragma unroll
        for (int b = 0; b < 8; ++b) {
            float x = pred[b * HW + pix];
            int t = tgt[b * HW + pix];
            float e = expf(-fabsf(x));
            float r = 1.f / (1.f + e);
            float p = (x >= 0.f) ? r : 1.f - r;                // stable sigmoid
            bce += fmaxf(x, 0.f) + log1pf(e) - x * (float)t;   // softplus - x*t
            vals[1 + b] = p;
            vals[9 + b] = t ? p : 0.f;
            vals[17 + b] = (float)t;
            sA += t ? 1.f - p : p;
        }
        sumA[pix] = sA;
        vals[0] = bce;
#pragma unroll
        for (int k = 0; k < 25; ++k)
#pragma unroll
            for (int o = 32; o; o >>= 1) vals[k] += __shfl_down(vals[k], o);
        int wave = tid >> 6, lane = tid & 63;
        if (lane == 0)
#pragma unroll
            for (int k = 0; k < 25; ++k) lds[wave][k] = vals[k];
        __syncthreads();
        if (tid < 25) {
            double s = 0.0;
#pragma unroll
            for (int wv = 0; wv < 12; ++wv) s += (double)lds[wv][tid];
            part2[blockIdx.x * 25 + tid] = s;
        }
    } else {
        // vert block 0 resets the 64 counter lines (visible to node 2 via boundary)
        if (blockIdx.x == NFB && tid < 64) *(unsigned*)(syncws + tid * 256) = 0u;
        // ---- vertical distance, word-parallel: thread = (32-row word, column) ----
        int vb = blockIdx.x - NFB;
        int wd = tid >> 6;                 // 0..11
        int wl = tid & 63;
        int b = vb / 6;
        int w = (vb % 6) * 64 + wl;

        const int* colp = tgt + b * HW + w + (wd * 32) * W;
        unsigned m = 0;
#pragma unroll
        for (int i = 0; i < 32; ++i)
            m |= (colp[i * W] != 0) ? (1u << i) : 0u;
        bmsh[wd][wl] = m;
        __syncthreads();

        unsigned mp = m, mn = ~m;
        int dfe_p = INF_I, dfe_n = INF_I, dbe_p = INF_I, dbe_n = INF_I;
        if (wd > 0) {
            int k = wd - 1; unsigned mm;
            while ((mm = bmsh[k][wl]) == 0 && k > 0) --k;
            if (mm) dfe_p = wd * 32 - 1 - (k * 32 + 31 - __clz(mm));
            k = wd - 1;
            while ((mm = ~bmsh[k][wl]) == 0 && k > 0) --k;
            if (mm) dfe_n = wd * 32 - 1 - (k * 32 + 31 - __clz(mm));
        }
        if (wd < 11) {
            int k = wd + 1; unsigned mm;
            while ((mm = bmsh[k][wl]) == 0 && k < 11) ++k;
            if (mm) dbe_p = k * 32 + (__ffs(mm) - 1) - (wd + 1) * 32;
            k = wd + 1;
            while ((mm = ~bmsh[k][wl]) == 0 && k < 11) ++k;
            if (mm) dbe_n = k * 32 + (__ffs(mm) - 1) - (wd + 1) * 32;
        }

        int dfp[32], dfn[32];
        int cp = dfe_p, cn = dfe_n;
#pragma unroll
        for (int i = 0; i < 32; ++i) {
            cp = ((mp >> i) & 1u) ? 0 : min(cp + 1, INF_I);
            cn = ((mn >> i) & 1u) ? 0 : min(cn + 1, INF_I);
            dfp[i] = cp; dfn[i] = cn;
        }
        unsigned* outc = g2u + b * HW + (wd * 32) * W + w;
        cp = dbe_p; cn = dbe_n;
#pragma unroll
        for (int i = 31; i >= 0; --i) {
            cp = ((mp >> i) & 1u) ? 0 : min(cp + 1, INF_I);
            cn = ((mn >> i) & 1u) ? 0 : min(cn + 1, INF_I);
            int dp = min(dfp[i], cp);
            int dn = min(dfn[i], cn);
            outc[i * W] = (unsigned)dp | ((unsigned)dn << 16);
        }
    }
}

// ---------------- launch 2: row envelope (workers) + parallel-poll combiner ----------------
__global__ __launch_bounds__(384) void k_rows(const unsigned* __restrict__ g2u,
                                              const float* __restrict__ sumA,
                                              const double* __restrict__ part2,
                                              char* __restrict__ syncws,
                                              float* __restrict__ out) {
    __shared__ float lfp[6][412], lfn[6][412];
    __shared__ double wpart[6];
    __shared__ double sval[25];
    int tid = threadIdx.x, bid = blockIdx.x;

    if (bid == NWK) {
        // ================= combiner block =================
        // loss1 partial reduction first (plain loads, node-boundary coherent)
        if (tid < 200) {
            int v = tid >> 3, sub = tid & 7;
            double s = 0.0;
            for (int blk = sub; blk < NFB; blk += 8) s += part2[blk * 25 + v];
#pragma unroll
            for (int o = 4; o; o >>= 1) s += __shfl_down(s, o, 8);
            if (sub == 0) sval[v] = s;
        }
        __syncthreads();
        double s2 = 0.0;
        if (tid < 64) {
            // parallel poll: lane l owns counter line l (8 workers each)
            unsigned c;
            do {
                c = atomicAdd((unsigned*)(syncws + tid * 256), 0u);
                if (__all(c == WPL)) break;
                __builtin_amdgcn_s_sleep(1);
            } while (1);
            // gather 8 slots per lane (independent atomic loads, fixed order)
            double r[8];
#pragma unroll
            for (int j = 0; j < 8; ++j)
                r[j] = __longlong_as_double(atomicAdd(
                    (unsigned long long*)(syncws + WS_SLOT + (j * 64 + tid) * 256), 0ull));
            s2 = ((((((r[0] + r[1]) + r[2]) + r[3]) + r[4]) + r[5]) + r[6]) + r[7];
#pragma unroll
            for (int o = 32; o; o >>= 1) s2 += __shfl_down(s2, o);
        }
        if (tid == 0) {
            double bce = sval[0] / (double)NTOT;
            double dsum = 0.0;
            for (int bb = 0; bb < 8; ++bb)
                dsum += (2.0 * sval[9 + bb] + 1e-5) / (sval[1 + bb] + sval[17 + bb] + 1e-5);
            double dice = dsum / 8.0;
            double loss1 = 0.5 * bce + (1.0 - dice);
            double loss2 = s2 / ((double)B * (double)B * (double)HW);
            out[0] = (float)(0.7 * loss1 + 0.03 * loss2);
        }
        return;
    }

    // ================= worker block: 6 rows, one per wave =================
    int wv = tid >> 6, lane = tid & 63;
    int bh = bid * 6 + wv;
    int b = bh / H, h = bh % H;
    const unsigned* row = g2u + b * HW + h * W;
    for (int q = lane; q < W; q += 64) {
        unsigned v = row[q];
        float dp = (float)(v & 0xFFFFu);
        float dn = (float)(v >> 16);
        int s = q + (q >> 4);
        lfp[wv][s] = dp * dp;              // exact: ints <= 1e4 -> d^2 <= 1e8
        lfn[wv][s] = dn * dn;
    }
    // wave-local producer/consumer: this wave only reads its own row
    asm volatile("s_waitcnt lgkmcnt(0)" ::: "memory");

    int base = 6 * lane - 8;
    float rp[22], rn[22];
#pragma unroll
    for (int r = 0; r < 22; ++r) {
        int j = base + r;
        j = j < 0 ? 0 : (j > W - 1 ? W - 1 : j);
        int s = j + (j >> 4);
        rp[r] = lfp[wv][s];
        rn[r] = lfn[wv][s];
    }
    const float DD[17] = {64.f,49.f,36.f,25.f,16.f,9.f,4.f,1.f,0.f,
                          1.f,4.f,9.f,16.f,25.f,36.f,49.f,64.f};
    float partial = 0.f;
#pragma unroll
    for (int q = 0; q < 6; ++q) {
        int i = 6 * lane + q;
        float Dp = 3.0e38f, Dn = 3.0e38f;
#pragma unroll
        for (int tt = 0; tt < 17; ++tt) {
            Dp = fminf(Dp, rp[q + tt] + DD[tt]);
            Dn = fminf(Dn, rn[q + tt] + DD[tt]);
        }
        if (Dp > 64.f || Dn > 64.f) {      // exactness not proven -> full row
            float fi = (float)i;
            for (int j = 0; j < W; ++j) {
                int s = j + (j >> 4);
                float d = fi - (float)j;
                Dp = fminf(Dp, fmaf(d, d, lfp[wv][s]));
                Dn = fminf(Dn, fmaf(d, d, lfn[wv][s]));
            }
        }
        float sdf = fabsf(sqrtf(Dp) - sqrtf(Dn));
        partial += sdf * sumA[h * W + i];
    }
    double v = partial;
#pragma unroll
    for (int o = 32; o; o >>= 1) v += __shfl_down(v, o);
    if (lane == 0) wpart[wv] = v;
    __syncthreads();

    if (tid == 0) {
        double bp = ((((wpart[0] + wpart[1]) + wpart[2]) + wpart[3]) + wpart[4]) + wpart[5];
        // private slot (atomicExch: deterministic, single writer), then signal.
        atomicExch((unsigned long long*)(syncws + WS_SLOT + bid * 256),
                   __double_as_longlong(bp));
        asm volatile("s_waitcnt vmcnt(0)" ::: "memory");   // slot visible before cnt
        atomicAdd((unsigned*)(syncws + (bid >> 3) * 256), 1u);
    }
}

extern "C" void kernel_launch(void* const* d_in, const int* in_sizes, int n_in,
                              void* d_out, int out_size, void* d_ws, size_t ws_size,
                              hipStream_t stream) {
    const float* pred = (const float*)d_in[0];
    const int* tgt = (const int*)d_in[1];
    float* out = (float*)d_out;
    char* ws = (char*)d_ws;
    double* part2 = (double*)(ws + WS_PART2);
    unsigned* g2u = (unsigned*)(ws + WS_G2U);
    float* sumA = (float*)(ws + WS_SUMA);

    k_stage1<<<NFB + NVB, 768, 0, stream>>>(pred, tgt, sumA, part2, g2u, ws);
    k_rows<<<NWK + 1, 384, 0, stream>>>(g2u, sumA, part2, ws, out);
}

// Round 13
// 23.773 us; speedup vs baseline: 1.9016x; 1.1344x over previous
//
#include <hip/hip_runtime.h>
#include <math.h>

#define B 8
#define H 384
#define W 384
#define HW (H*W)
#define NTOT (B*HW)
#define INF_I 10000
#define NFB 192            // fused BCE/dice/sumA blocks (768 thr, 1 pix/thread)
#define NVB 48             // bit-packer blocks (tgt -> column-major masks)
#define NWK 256            // row workers: (image, 12-row stripe)
#define CMB (NFB+NVB+NWK)  // combiner block id (496)
#define TOKEN 0x7E57F1A6u

// ws layout (bytes):
//   flags @ 0      : 496 lines x 256B  (fused f: line f; packer p: 192+p; worker w: 240+w)
//   slot  @ 131072 : 256 lines x 256B  (u64 loss2 partial per worker)
//   part2 @ 262144 : NFB*25 doubles (38400 B, atomic-written)
//   cw    @ 311296 : 8 img x 12 words x 384 cols u32 (147456 B, atomic-written)
//   sumA  @ 462848 : HW float (atomic-written)
#define WS_SLOT  131072
#define WS_PART2 262144
#define WS_CW    311296
#define WS_SUMA  462848

__global__ __launch_bounds__(768) void k_all(const float* __restrict__ pred,
                                             const int* __restrict__ tgt,
                                             char* __restrict__ ws,
                                             float* __restrict__ out) {
    __shared__ float lds[12][25];
    __shared__ unsigned lcw[12][384];
    __shared__ float lfp[12][412], lfn[12][412];
    __shared__ double wpart[12];
    __shared__ double sval[25];
    __shared__ double sl2[4];
    int tid = threadIdx.x, bid = blockIdx.x;
    unsigned* flags = (unsigned*)ws;
    double* part2 = (double*)(ws + WS_PART2);
    unsigned* cwG = (unsigned*)(ws + WS_CW);
    float* sumA = (float*)(ws + WS_SUMA);

    if (bid < NFB) {
        // ============ fused BCE + dice partials + sumA (1 pixel/thread) ============
        int pix = bid * 768 + tid;
        float vals[25];                    // 0=bce, 1+b=p, 9+b=p*t, 17+b=t
        float sA = 0.f, bce = 0.f;
#pragma unroll
        for (int b = 0; b < 8; ++b) {
            float x = pred[b * HW + pix];
            int t = tgt[b * HW + pix];
            float e = expf(-fabsf(x));
            float r = 1.f / (1.f + e);
            float p = (x >= 0.f) ? r : 1.f - r;                // stable sigmoid
            bce += fmaxf(x, 0.f) + log1pf(e) - x * (float)t;   // softplus - x*t
            vals[1 + b] = p;
            vals[9 + b] = t ? p : 0.f;
            vals[17 + b] = (float)t;
            sA += t ? 1.f - p : p;
        }
        atomicExch((unsigned*)&sumA[pix], __float_as_uint(sA));   // coherent publish
        vals[0] = bce;
#pragma unroll
        for (int k = 0; k < 25; ++k)
#pragma unroll
            for (int o = 32; o; o >>= 1) vals[k] += __shfl_down(vals[k], o);
        int wave = tid >> 6, lane = tid & 63;
        if (lane == 0)
#pragma unroll
            for (int k = 0; k < 25; ++k) lds[wave][k] = vals[k];
        __syncthreads();
        if (tid < 25) {
            double s = 0.0;
#pragma unroll
            for (int wv = 0; wv < 12; ++wv) s += (double)lds[wv][tid];
            atomicExch((unsigned long long*)&part2[bid * 25 + tid],
                       (unsigned long long)__double_as_longlong(s));
        }
        __syncthreads();                       // drains all threads' atomics
        if (tid == 0) atomicExch(&flags[bid * 64], TOKEN);
    } else if (bid < NFB + NVB) {
        // ============ packer: tgt -> column-major 32-row bit words ============
        int p = bid - NFB;
        int wd = tid >> 6, wl = tid & 63;
        int b = p / 6, w = (p % 6) * 64 + wl;
        const int* colp = tgt + b * HW + w + (wd * 32) * W;
        unsigned m = 0;
#pragma unroll
        for (int i = 0; i < 32; ++i)
            m |= (colp[i * W] != 0) ? (1u << i) : 0u;
        atomicExch(&cwG[(b * 12 + wd) * 384 + w], m);
        __syncthreads();
        if (tid == 0) atomicExch(&flags[(192 + p) * 64], TOKEN);
    } else if (bid < CMB) {
        // ============ worker: (image b, 12-row stripe) ============
        int w = bid - (NFB + NVB);
        int b = w >> 5, stripe = w & 31;
        int h0 = stripe * 12;
        // poll producers: lanes 0-5 packer flags of image b, 6-11 fused flags of rows
        if (tid < 12) {
            int line = (tid < 6) ? (192 + 6 * b + tid) * 64
                                 : (6 * stripe + (tid - 6)) * 64;
            while (atomicAdd(&flags[line], 0u) != TOKEN) __builtin_amdgcn_s_sleep(8);
        }
        __syncthreads();
        // stage this image's bit words (18 KB, L3-hot)
        {
            const unsigned* src = cwG + b * 12 * 384;
            unsigned* dst = &lcw[0][0];
            for (int i = tid; i < 12 * 384; i += 768) dst[i] = src[i];
        }
        __syncthreads();

        // ---- vertical EDT for rows h0..h0+11, one (column, pos/neg) per thread ----
        {
            int col = tid >> 1, pn = tid & 1;
            unsigned cwv[12];
#pragma unroll
            for (int j = 0; j < 12; ++j) {
                unsigned mm = lcw[j][col];
                cwv[j] = pn ? ~mm : mm;
            }
            int wd0 = h0 >> 5, off = h0 & 31;
            // carry from above (nearest set bit at row < h0)
            int cin = INF_I;
            {
                unsigned mm = off ? (cwv[wd0] & ((1u << off) - 1u)) : 0u;
                int j = wd0;
                while (mm == 0u && j > 0) mm = cwv[--j];
                if (mm) cin = h0 - (j * 32 + (31 - __clz(mm)));
            }
            // carry from below (nearest set bit at row >= h0+12)
            int cinb = INF_I;
            int he = h0 + 12;
            if (he < H) {
                int j1 = he >> 5, off1 = he & 31;
                unsigned mm = cwv[j1] & (off1 ? ~((1u << off1) - 1u) : 0xFFFFFFFFu);
                int j = j1;
                while (mm == 0u && j < 11) mm = cwv[++j];
                if (mm) cinb = (j * 32 + (__ffs(mm) - 1)) - (h0 + 11);
            }
            unsigned lo = cwv[wd0];
            unsigned hi = (wd0 < 11) ? cwv[wd0 + 1] : 0u;
            unsigned long long win = ((((unsigned long long)hi) << 32) | lo) >> off;
            int df[12];
            int c = cin;
#pragma unroll
            for (int r = 0; r < 12; ++r) {
                c = ((win >> r) & 1ull) ? 0 : min(c + 1, INF_I);
                df[r] = c;
            }
            int cb = cinb;
            int s = col + (col >> 4);
#pragma unroll
            for (int r = 11; r >= 0; --r) {
                cb = ((win >> r) & 1ull) ? 0 : min(cb + 1, INF_I);
                int d = min(df[r], cb);
                float fd = (float)d;
                if (pn) lfn[r][s] = fd * fd;   // exact: d<=1e4 -> d^2<=1e8
                else    lfp[r][s] = fd * fd;
            }
        }
        __syncthreads();

        // ---- row lower-envelope (17-tap window + provable full-row fallback) ----
        int wv = tid >> 6, lane = tid & 63;
        int h = h0 + wv;
        int base = 6 * lane - 8;
        float rp[22], rn[22];
#pragma unroll
        for (int r = 0; r < 22; ++r) {
            int j = base + r;
            j = j < 0 ? 0 : (j > W - 1 ? W - 1 : j);
            int s = j + (j >> 4);
            rp[r] = lfp[wv][s];
            rn[r] = lfn[wv][s];
        }
        const float DD[17] = {64.f,49.f,36.f,25.f,16.f,9.f,4.f,1.f,0.f,
                              1.f,4.f,9.f,16.f,25.f,36.f,49.f,64.f};
        float partial = 0.f;
#pragma unroll
        for (int q = 0; q < 6; ++q) {
            int i = 6 * lane + q;
            float Dp = 3.0e38f, Dn = 3.0e38f;
#pragma unroll
            for (int tt = 0; tt < 17; ++tt) {
                Dp = fminf(Dp, rp[q + tt] + DD[tt]);
                Dn = fminf(Dn, rn[q + tt] + DD[tt]);
            }
            if (Dp > 64.f || Dn > 64.f) {      // exactness not proven -> full row
                float fi = (float)i;
                for (int j = 0; j < W; ++j) {
                    int s = j + (j >> 4);
                    float d = fi - (float)j;
                    Dp = fminf(Dp, fmaf(d, d, lfp[wv][s]));
                    Dn = fminf(Dn, fmaf(d, d, lfn[wv][s]));
                }
            }
            float sdf = fabsf(sqrtf(Dp) - sqrtf(Dn));
            partial += sdf * sumA[h * W + i];
        }
        double v = partial;
#pragma unroll
        for (int o = 32; o; o >>= 1) v += __shfl_down(v, o);
        if (lane == 0) wpart[wv] = v;
        __syncthreads();
        if (tid == 0) {
            double bp = 0.0;
#pragma unroll
            for (int k = 0; k < 12; ++k) bp += wpart[k];
            atomicExch((unsigned long long*)(ws + WS_SLOT + w * 256),
                       (unsigned long long)__double_as_longlong(bp));
            asm volatile("s_waitcnt vmcnt(0)" ::: "memory");  // slot before flag
            atomicExch(&flags[(240 + w) * 64], TOKEN);
        }
    } else {
        // ============ combiner ============
        if (tid < 448) {
            int line = (tid < 192) ? tid * 64 : (240 + (tid - 192)) * 64;
            while (atomicAdd(&flags[line], 0u) != TOKEN) __builtin_amdgcn_s_sleep(8);
        }
        __syncthreads();
        if (tid < 200) {
            int v = tid >> 3, sub = tid & 7;
            double s = 0.0;
            for (int blk = sub; blk < NFB; blk += 8) s += part2[blk * 25 + v];
#pragma unroll
            for (int o = 4; o; o >>= 1) s += __shfl_down(s, o, 8);
            if (sub == 0) sval[v] = s;
        }
        double s2 = 0.0;
        if (tid < 256)
            s2 = *(const double*)(ws + WS_SLOT + tid * 256);
#pragma unroll
        for (int o = 32; o; o >>= 1) s2 += __shfl_down(s2, o);
        if (tid < 256 && (tid & 63) == 0) sl2[tid >> 6] = s2;
        __syncthreads();
        if (tid == 0) {
            double bce = sval[0] / (double)NTOT;
            double dsum = 0.0;
            for (int bb = 0; bb < 8; ++bb)
                dsum += (2.0 * sval[9 + bb] + 1e-5) / (sval[1 + bb] + sval[17 + bb] + 1e-5);
            double dice = dsum / 8.0;
            double loss1 = 0.5 * bce + (1.0 - dice);
            double loss2 = (sl2[0] + sl2[1] + sl2[2] + sl2[3])
                         / ((double)B * (double)B * (double)HW);
            out[0] = (float)(0.7 * loss1 + 0.03 * loss2);
        }
    }
}

extern "C" void kernel_launch(void* const* d_in, const int* in_sizes, int n_in,
                              void* d_out, int out_size, void* d_ws, size_t ws_size,
                              hipStream_t stream) {
    const float* pred = (const float*)d_in[0];
    const int* tgt = (const int*)d_in[1];
    float* out = (float*)d_out;
    char* ws = (char*)d_ws;

    k_all<<<CMB + 1, 768, 0, stream>>>(pred, tgt, ws, out);
}

// Round 14
// 21.433 us; speedup vs baseline: 2.1093x; 1.1092x over previous
//
#include <hip/hip_runtime.h>
#include <math.h>

#define B 8
#define H 384
#define W 384
#define HW (H*W)
#define NTOT (B*HW)
#define INF_I 10000
#define NFB 192            // fused BCE/dice/sumA blocks (768 thr, 1 pix/thread)
#define NVB 48             // bit-packer blocks (tgt -> column-major masks)
#define NWK 256            // row workers: (image, 12-row stripe)
#define CMB (NFB+NVB+NWK)  // combiner block id (496)
#define TOKEN 0x7E57F1A6u

// ws layout (bytes):
//   flags @ 0      : 496 lines x 256B  (fused f: line f; packer p: 192+p; worker w: 240+w)
//   slot  @ 131072 : 256 lines x 256B  (u64 loss2 partial per worker)
//   part2 @ 262144 : NFB*25 doubles (38400 B, atomic-written)
//   cw    @ 311296 : 8 img x 12 words x 384 cols u32 (147456 B, atomic-written)
//   sumA  @ 462848 : HW float (atomic-written)
#define WS_SLOT  131072
#define WS_PART2 262144
#define WS_CW    311296
#define WS_SUMA  462848

__global__ __launch_bounds__(768) void k_all(const float* __restrict__ pred,
                                             const int* __restrict__ tgt,
                                             char* __restrict__ ws,
                                             float* __restrict__ out) {
    __shared__ float lds[12][25];
    __shared__ unsigned lcw[12][384];
    __shared__ float lfp[12][412], lfn[12][412];
    __shared__ double wpart[12];
    __shared__ double sval[25];
    __shared__ double sl2[4];
    int tid = threadIdx.x, bid = blockIdx.x;
    unsigned* flags = (unsigned*)ws;
    double* part2 = (double*)(ws + WS_PART2);
    unsigned* cwG = (unsigned*)(ws + WS_CW);
    float* sumA = (float*)(ws + WS_SUMA);

    if (bid < NFB) {
        // ============ fused BCE + dice partials + sumA (1 pixel/thread) ============
        int pix = bid * 768 + tid;
        float vals[25];                    // 0=bce, 1+b=p, 9+b=p*t, 17+b=t
        float sA = 0.f, bce = 0.f;
#pragma unroll
        for (int b = 0; b < 8; ++b) {
            float x = pred[b * HW + pix];
            int t = tgt[b * HW + pix];
            // cheap HW transcendentals: err ~1e-7 rel, 5 orders below threshold
            float e = __builtin_amdgcn_exp2f(fabsf(x) * -1.442695041f);  // exp(-|x|)
            float rc = __builtin_amdgcn_rcpf(1.f + e);                   // 1/(1+e)
            float p = (x >= 0.f) ? rc : 1.f - rc;                        // sigmoid
            float l1p = __builtin_amdgcn_logf(1.f + e) * 0.69314718056f; // log1p(e)
            bce += fmaxf(x, 0.f) + l1p - x * (float)t;                   // softplus - x*t
            vals[1 + b] = p;
            vals[9 + b] = t ? p : 0.f;
            vals[17 + b] = (float)t;
            sA += t ? 1.f - p : p;
        }
        atomicExch((unsigned*)&sumA[pix], __float_as_uint(sA));   // coherent publish
        vals[0] = bce;
#pragma unroll
        for (int k = 0; k < 25; ++k)
#pragma unroll
            for (int o = 32; o; o >>= 1) vals[k] += __shfl_down(vals[k], o);
        int wave = tid >> 6, lane = tid & 63;
        if (lane == 0)
#pragma unroll
            for (int k = 0; k < 25; ++k) lds[wave][k] = vals[k];
        __syncthreads();
        if (tid < 25) {
            double s = 0.0;
#pragma unroll
            for (int wv = 0; wv < 12; ++wv) s += (double)lds[wv][tid];
            atomicExch((unsigned long long*)&part2[bid * 25 + tid],
                       (unsigned long long)__double_as_longlong(s));
        }
        __syncthreads();                       // drains all threads' atomics
        if (tid == 0) atomicExch(&flags[bid * 64], TOKEN);
    } else if (bid < NFB + NVB) {
        // ============ packer: tgt -> column-major 32-row bit words ============
        int p = bid - NFB;
        int wd = tid >> 6, wl = tid & 63;
        int b = p / 6, w = (p % 6) * 64 + wl;
        const int* colp = tgt + b * HW + w + (wd * 32) * W;
        unsigned m = 0;
#pragma unroll
        for (int i = 0; i < 32; ++i)
            m |= (colp[i * W] != 0) ? (1u << i) : 0u;
        atomicExch(&cwG[(b * 12 + wd) * 384 + w], m);
        __syncthreads();
        if (tid == 0) atomicExch(&flags[(192 + p) * 64], TOKEN);
    } else if (bid < CMB) {
        // ============ worker: (image b, 12-row stripe) ============
        int w = bid - (NFB + NVB);
        int b = w >> 5, stripe = w & 31;
        int h0 = stripe * 12;
        // poll packer flags only (EDT does not need sumA yet)
        if (tid < 6) {
            int line = (192 + 6 * b + tid) * 64;
            while (atomicAdd(&flags[line], 0u) != TOKEN) __builtin_amdgcn_s_sleep(8);
        }
        __syncthreads();
        // stage this image's bit words (18 KB, L3-hot)
        {
            const unsigned* src = cwG + b * 12 * 384;
            unsigned* dst = &lcw[0][0];
            for (int i = tid; i < 12 * 384; i += 768) dst[i] = src[i];
        }
        __syncthreads();

        // ---- vertical EDT for rows h0..h0+11, one (column, pos/neg) per thread ----
        {
            int col = tid >> 1, pn = tid & 1;
            unsigned cwv[12];
#pragma unroll
            for (int j = 0; j < 12; ++j) {
                unsigned mm = lcw[j][col];
                cwv[j] = pn ? ~mm : mm;
            }
            int wd0 = h0 >> 5, off = h0 & 31;
            // carry from above (nearest set bit at row < h0)
            int cin = INF_I;
            {
                unsigned mm = off ? (cwv[wd0] & ((1u << off) - 1u)) : 0u;
                int j = wd0;
                while (mm == 0u && j > 0) mm = cwv[--j];
                if (mm) cin = h0 - (j * 32 + (31 - __clz(mm)));
            }
            // carry from below (nearest set bit at row >= h0+12)
            int cinb = INF_I;
            int he = h0 + 12;
            if (he < H) {
                int j1 = he >> 5, off1 = he & 31;
                unsigned mm = cwv[j1] & (off1 ? ~((1u << off1) - 1u) : 0xFFFFFFFFu);
                int j = j1;
                while (mm == 0u && j < 11) mm = cwv[++j];
                if (mm) cinb = (j * 32 + (__ffs(mm) - 1)) - (h0 + 11);
            }
            unsigned lo = cwv[wd0];
            unsigned hi = (wd0 < 11) ? cwv[wd0 + 1] : 0u;
            unsigned long long win = ((((unsigned long long)hi) << 32) | lo) >> off;
            int df[12];
            int c = cin;
#pragma unroll
            for (int r = 0; r < 12; ++r) {
                c = ((win >> r) & 1ull) ? 0 : min(c + 1, INF_I);
                df[r] = c;
            }
            int cb = cinb;
            int s = col + (col >> 4);
#pragma unroll
            for (int r = 11; r >= 0; --r) {
                cb = ((win >> r) & 1ull) ? 0 : min(cb + 1, INF_I);
                int d = min(df[r], cb);
                float fd = (float)d;
                if (pn) lfn[r][s] = fd * fd;   // exact: d<=1e4 -> d^2<=1e8
                else    lfp[r][s] = fd * fd;
            }
        }
        // now wait for the fused blocks that produce this stripe's sumA rows
        if (tid < 6) {
            int line = (6 * stripe + tid) * 64;
            while (atomicAdd(&flags[line], 0u) != TOKEN) __builtin_amdgcn_s_sleep(8);
        }
        __syncthreads();   // orders EDT LDS writes AND the sumA flag wait

        // ---- row lower-envelope (17-tap window + provable full-row fallback) ----
        int wv = tid >> 6, lane = tid & 63;
        int h = h0 + wv;
        int base = 6 * lane - 8;
        float rp[22], rn[22];
#pragma unroll
        for (int r = 0; r < 22; ++r) {
            int j = base + r;
            j = j < 0 ? 0 : (j > W - 1 ? W - 1 : j);
            int s = j + (j >> 4);
            rp[r] = lfp[wv][s];
            rn[r] = lfn[wv][s];
        }
        const float DD[17] = {64.f,49.f,36.f,25.f,16.f,9.f,4.f,1.f,0.f,
                              1.f,4.f,9.f,16.f,25.f,36.f,49.f,64.f};
        float partial = 0.f;
#pragma unroll
        for (int q = 0; q < 6; ++q) {
            int i = 6 * lane + q;
            float Dp = 3.0e38f, Dn = 3.0e38f;
#pragma unroll
            for (int tt = 0; tt < 17; ++tt) {
                Dp = fminf(Dp, rp[q + tt] + DD[tt]);
                Dn = fminf(Dn, rn[q + tt] + DD[tt]);
            }
            if (Dp > 64.f || Dn > 64.f) {      // exactness not proven -> full row
                float fi = (float)i;
                for (int j = 0; j < W; ++j) {
                    int s = j + (j >> 4);
                    float d = fi - (float)j;
                    Dp = fminf(Dp, fmaf(d, d, lfp[wv][s]));
                    Dn = fminf(Dn, fmaf(d, d, lfn[wv][s]));
                }
            }
            float sdf = fabsf(sqrtf(Dp) - sqrtf(Dn));
            partial += sdf * sumA[h * W + i];
        }
        double v = partial;
#pragma unroll
        for (int o = 32; o; o >>= 1) v += __shfl_down(v, o);
        if (lane == 0) wpart[wv] = v;
        __syncthreads();
        if (tid == 0) {
            double bp = 0.0;
#pragma unroll
            for (int k = 0; k < 12; ++k) bp += wpart[k];
            atomicExch((unsigned long long*)(ws + WS_SLOT + w * 256),
                       (unsigned long long)__double_as_longlong(bp));
            asm volatile("s_waitcnt vmcnt(0)" ::: "memory");  // slot before flag
            atomicExch(&flags[(240 + w) * 64], TOKEN);
        }
    } else {
        // ============ combiner ============
        if (tid < 448) {
            int line = (tid < 192) ? tid * 64 : (240 + (tid - 192)) * 64;
            while (atomicAdd(&flags[line], 0u) != TOKEN) __builtin_amdgcn_s_sleep(8);
        }
        __syncthreads();
        if (tid < 200) {
            int v = tid >> 3, sub = tid & 7;
            double s = 0.0;
            for (int blk = sub; blk < NFB; blk += 8) s += part2[blk * 25 + v];
#pragma unroll
            for (int o = 4; o; o >>= 1) s += __shfl_down(s, o, 8);
            if (sub == 0) sval[v] = s;
        }
        double s2 = 0.0;
        if (tid < 256)
            s2 = *(const double*)(ws + WS_SLOT + tid * 256);
#pragma unroll
        for (int o = 32; o; o >>= 1) s2 += __shfl_down(s2, o);
        if (tid < 256 && (tid & 63) == 0) sl2[tid >> 6] = s2;
        __syncthreads();
        if (tid == 0) {
            double bce = sval[0] / (double)NTOT;
            double dsum = 0.0;
            for (int bb = 0; bb < 8; ++bb)
                dsum += (2.0 * sval[9 + bb] + 1e-5) / (sval[1 + bb] + sval[17 + bb] + 1e-5);
            double dice = dsum / 8.0;
            double loss1 = 0.5 * bce + (1.0 - dice);
            double loss2 = (sl2[0] + sl2[1] + sl2[2] + sl2[3])
                         / ((double)B * (double)B * (double)HW);
            out[0] = (float)(0.7 * loss1 + 0.03 * loss2);
        }
    }
}

extern "C" void kernel_launch(void* const* d_in, const int* in_sizes, int n_in,
                              void* d_out, int out_size, void* d_ws, size_t ws_size,
                              hipStream_t stream) {
    const float* pred = (const float*)d_in[0];
    const int* tgt = (const int*)d_in[1];
    float* out = (float*)d_out;
    char* ws = (char*)d_ws;

    k_all<<<CMB + 1, 768, 0, stream>>>(pred, tgt, ws, out);
}